// Round 4
// baseline (293.372 us; speedup 1.0000x reference)
//
#include <hip/hip_runtime.h>
#include <hip/hip_bf16.h>
#include <math.h>

#define BATCH 4

typedef __bf16 bf16x8 __attribute__((ext_vector_type(8)));
typedef float f32x4 __attribute__((ext_vector_type(4)));

#define LDSTRIDE 40  // bf16 units per LDS row (80 B): conflict-free b128 access

// ---------------- K1: convert teacher rows to bf16 (extra rows pre-normalized) ----------------
__global__ __launch_bounds__(256) void convert_kernel(const float* __restrict__ teacher,
                                                      const int* __restrict__ ref_perm,
                                                      __bf16* __restrict__ Abf,
                                                      __bf16* __restrict__ Bbf,
                                                      float* __restrict__ invnorm,
                                                      float* __restrict__ acc) {
    int blk = blockIdx.x;            // b*4352 + r
    int b = blk / 4352;
    int r = blk - b * 4352;
    int t = threadIdx.x;
    if (blk == 0 && t < 4) acc[t] = 0.f;   // replaces memset dispatch
    const float* src;
    __bf16* dst;
    bool isB = (r >= 256);
    if (!isB) {
        src = teacher + (((size_t)b * 8 + 0) * 1024 + ref_perm[r]) * 1024;
        dst = Abf + ((size_t)b * 256 + r) * 1024;
    } else {
        int m = r - 256;
        int frame = 1 + 2 * (m >> 10), p = m & 1023;
        src = teacher + (((size_t)b * 8 + frame) * 1024 + p) * 1024;
        dst = Bbf + ((size_t)b * 4096 + m) * 1024;
    }
    float4 v = ((const float4*)src)[t];
    float scale = 1.0f;
    __shared__ float red[4];
    if (isB) {
        float s = v.x * v.x + v.y * v.y + v.z * v.z + v.w * v.w;
        for (int o = 32; o > 0; o >>= 1) s += __shfl_xor(s, o);
        if ((t & 63) == 0) red[t >> 6] = s;
        __syncthreads();
        float tot = red[0] + red[1] + red[2] + red[3];
        scale = 1.0f / fmaxf(sqrtf(tot), 1e-12f);
        if (t == 0) invnorm[b * 4096 + (r - 256)] = scale;
    }
    __bf16 o4[4] = {(__bf16)(v.x * scale), (__bf16)(v.y * scale),
                    (__bf16)(v.z * scale), (__bf16)(v.w * scale)};
    ((uint2*)dst)[t] = *(uint2*)o4;
}

// ---------------- K2: bf16 MFMA GEMM, 8 waves/block (2 waves/SIMD) ----------------
__global__ __launch_bounds__(512) void mfma_gemm_kernel(const __bf16* __restrict__ Abf,
                                                        const __bf16* __restrict__ Bbf,
                                                        __bf16* __restrict__ scoresb) {
    int mt = blockIdx.x;    // 0..31
    int nt = blockIdx.y;    // 0..1
    int b  = blockIdx.z;    // 0..3
    int t = threadIdx.x;
    int lane = t & 63, wave = t >> 6;      // 8 waves
    int wn0 = (wave & 1) * 64;             // N offset (two 64-halves)
    int wm0 = (wave >> 1) * 32;            // M offset (four 32-slices)
    int l15 = lane & 15, l4 = lane >> 4;

    __shared__ __bf16 As[128 * LDSTRIDE];
    __shared__ __bf16 Bs[128 * LDSTRIDE];

    const __bf16* Ab = Abf + ((size_t)b * 256 + nt * 128) * 1024;
    const __bf16* Bb = Bbf + ((size_t)b * 4096 + mt * 128) * 1024;

    int row0 = t >> 2, kc0 = t & 3;        // 512 threads cover 128x32 exactly once

    f32x4 acc[4][2] = {};

    for (int k0 = 0; k0 < 1024; k0 += 32) {
        uint4 a0 = *(const uint4*)(Ab + (size_t)row0 * 1024 + k0 + kc0 * 8);
        uint4 b0 = *(const uint4*)(Bb + (size_t)row0 * 1024 + k0 + kc0 * 8);
        __syncthreads();   // prev iter's frag reads complete
        *(uint4*)(As + row0 * LDSTRIDE + kc0 * 8) = a0;
        *(uint4*)(Bs + row0 * LDSTRIDE + kc0 * 8) = b0;
        __syncthreads();
        bf16x8 af[4], bfr[2];
#pragma unroll
        for (int i = 0; i < 4; i++)
            af[i] = *(const bf16x8*)(As + (wn0 + i * 16 + l15) * LDSTRIDE + l4 * 8);
#pragma unroll
        for (int j = 0; j < 2; j++)
            bfr[j] = *(const bf16x8*)(Bs + (wm0 + j * 16 + l15) * LDSTRIDE + l4 * 8);
#pragma unroll
        for (int i = 0; i < 4; i++)
#pragma unroll
            for (int j = 0; j < 2; j++)
                acc[i][j] = __builtin_amdgcn_mfma_f32_16x16x32_bf16(af[i], bfr[j], acc[i][j], 0, 0, 0);
    }

    __bf16* outp = scoresb + ((size_t)b * 256 + nt * 128) * 4096 + (size_t)mt * 128;
#pragma unroll
    for (int i = 0; i < 4; i++)
#pragma unroll
        for (int j = 0; j < 2; j++)
#pragma unroll
            for (int r = 0; r < 4; r++) {
                int n = wn0 + i * 16 + l4 * 4 + r;
                int m = wm0 + j * 16 + l15;
                outp[(size_t)n * 4096 + m] = (__bf16)acc[i][j][r];
            }
}

// ---------------- K3: fused top-8 -> exact rescore -> top-4 -> KL ----------------
__global__ __launch_bounds__(256) void topk_kl_kernel(const __bf16* __restrict__ scoresb,
                                                      const float* __restrict__ teacher,
                                                      const float* __restrict__ student,
                                                      const int* __restrict__ ref_perm,
                                                      const int* __restrict__ shared_perm,
                                                      const float* __restrict__ invnorm,
                                                      float* __restrict__ acc) {
    int row = blockIdx.x;  // b*256+n
    int b = row >> 8, n = row & 255;
    int t = threadIdx.x;
    int lane = t & 63, wave = t >> 6;

    __shared__ float rt[1024], rs[1024], st[1024], ss[1024];
    __shared__ float sh8[8][1024];
    __shared__ float cval[32];
    __shared__ int cidx[32];
    __shared__ int cand_i[8];
    __shared__ float exact_v[8];
    __shared__ int wslot[4];
    __shared__ float res3[3];
    if (t < 3) res3[t] = 0.f;

    const float* Tb = teacher + (size_t)b * 8 * 1024 * 1024;
    const float* Sb = student + (size_t)b * 4 * 1024 * 1024;

    int rp = ref_perm[n];
    ((float4*)rt)[t] = ((const float4*)(Tb + (size_t)rp * 1024))[t];
    ((float4*)rs)[t] = ((const float4*)(Sb + (size_t)rp * 1024))[t];

    // ---- coalesced score load: thread t owns m in [16t, 16t+16) ----
    const __bf16* srow = scoresb + (size_t)row * 4096;
    __bf16 xs[16];
    *(uint4*)xs = ((const uint4*)srow)[2 * t];
    *(uint4*)(xs + 8) = ((const uint4*)srow)[2 * t + 1];

    // per-thread sorted top-8 (static register indices only)
    float v[8]; int ix[8];
#pragma unroll
    for (int i = 0; i < 8; i++) { v[i] = -1e38f; ix[i] = -1; }
#pragma unroll
    for (int jj = 0; jj < 16; jj++) {
        float xv = (float)xs[jj]; int xm = t * 16 + jj;
        if (xv > v[7]) {
            v[7] = xv; ix[7] = xm;
#pragma unroll
            for (int i = 7; i > 0; i--)
                if (v[i] > v[i - 1]) {
                    float tv = v[i]; v[i] = v[i - 1]; v[i - 1] = tv;
                    int ti = ix[i]; ix[i] = ix[i - 1]; ix[i - 1] = ti;
                }
        }
    }
    // wave-level top-8: butterfly argmax on heads + static pop
    for (int r = 0; r < 8; r++) {
        float bv = v[0]; int bi = ix[0];
        for (int o = 32; o > 0; o >>= 1) {
            float ov = __shfl_xor(bv, o); int oi = __shfl_xor(bi, o);
            if (ov > bv || (ov == bv && oi > bi)) { bv = ov; bi = oi; }
        }
        if (lane == 0) { cval[wave * 8 + r] = bv; cidx[wave * 8 + r] = bi; }
        if (bi == ix[0]) {
            v[0] = v[1]; ix[0] = ix[1];
            v[1] = v[2]; ix[1] = ix[2];
            v[2] = v[3]; ix[2] = ix[3];
            v[3] = v[4]; ix[3] = ix[4];
            v[4] = v[5]; ix[4] = ix[5];
            v[5] = v[6]; ix[5] = ix[6];
            v[6] = v[7]; ix[6] = ix[7];
            v[7] = -1e38f; ix[7] = -1;
        }
    }
    __syncthreads();
    // block merge: wave 0 reduces 32 candidates -> top-8
    if (wave == 0) {
        float mv = (lane < 32) ? cval[lane] : -1e38f;
        int mi = (lane < 32) ? cidx[lane] : -1;
        for (int r = 0; r < 8; r++) {
            float bv = mv; int bi = mi;
            for (int o = 32; o > 0; o >>= 1) {
                float ov = __shfl_xor(bv, o); int oi = __shfl_xor(bi, o);
                if (ov > bv || (ov == bv && oi > bi)) { bv = ov; bi = oi; }
            }
            if (lane == 0) cand_i[r] = bi;
            if (bi == mi) mv = -1e38f;
        }
    }
    __syncthreads();
    // stage all 8 candidate rows into LDS (read once, reused by rescore + KL)
#pragma unroll
    for (int c = 0; c < 8; c++) {
        int m = cand_i[c];
        int frame = 1 + 2 * (m >> 10), p = m & 1023;
        ((float4*)sh8[c])[t] = ((const float4*)(Tb + ((size_t)frame * 1024 + p) * 1024))[t];
    }
    __syncthreads();
    // exact fp32 rescore from LDS
    for (int c = wave; c < 8; c += 4) {
        float s = 0.f;
#pragma unroll
        for (int jj = 0; jj < 16; jj++) {
            int d = lane + 64 * jj;
            s = fmaf(rt[d], sh8[c][d], s);
        }
        for (int o = 32; o > 0; o >>= 1) s += __shfl_xor(s, o);
        if (lane == 0) exact_v[c] = s * invnorm[b * 4096 + cand_i[c]];
    }
    __syncthreads();
    if (t == 0) {
        unsigned used = 0;
        for (int r = 0; r < 4; r++) {
            float bv = -1e38f; int bc = 0;
            for (int c = 0; c < 8; c++)
                if (!(used & (1u << c)) && exact_v[c] > bv) { bv = exact_v[c]; bc = c; }
            used |= 1u << bc;
            wslot[r] = bc;
        }
    }
    __syncthreads();
    const float* shp[4] = {sh8[wslot[0]], sh8[wslot[1]], sh8[wslot[2]], sh8[wslot[3]]};

    int sp = shared_perm[n];
    for (int ti = 0; ti < 3; ti++) {
        int t_idx = 2 * ti + 2;
        int s_idx = ti + 1;
        __syncthreads();   // prev iteration's st/ss reads done
        ((float4*)st)[t] = ((const float4*)(Tb + ((size_t)t_idx * 1024 + sp) * 1024))[t];
        ((float4*)ss)[t] = ((const float4*)(Sb + ((size_t)s_idx * 1024 + sp) * 1024))[t];
        __syncthreads();

        for (int r = wave; r < 9; r += 4) {
            const float *At, *Bt, *Asx, *Bsx;
            int branch;
            if (r == 0)      { At = rt; Bt = st;         Asx = rs; Bsx = ss;         branch = 0; }
            else if (r < 5)  { At = rt; Bt = shp[r - 1]; Asx = rs; Bsx = shp[r - 1]; branch = 1; }
            else             { At = st; Bt = shp[r - 5]; Asx = ss; Bsx = shp[r - 5]; branch = 2; }

            float dt[16], ds[16];
            float mt = -1e38f, ms = -1e38f;
#pragma unroll
            for (int j = 0; j < 16; j++) {
                int d = lane + 64 * j;
                dt[j] = At[d] - Bt[d];
                ds[j] = Asx[d] - Bsx[d];
                mt = fmaxf(mt, dt[j]);
                ms = fmaxf(ms, ds[j]);
            }
            for (int o = 32; o > 0; o >>= 1) {
                mt = fmaxf(mt, __shfl_xor(mt, o));
                ms = fmaxf(ms, __shfl_xor(ms, o));
            }
            float Zt = 0.f, Zs = 0.f, Tn = 0.f;
#pragma unroll
            for (int j = 0; j < 16; j++) {
                float et = __expf(dt[j] - mt);
                Zt += et;
                Zs += __expf(ds[j] - ms);
                Tn += et * (dt[j] - ds[j]);
            }
            for (int o = 32; o > 0; o >>= 1) {
                Zt += __shfl_xor(Zt, o);
                Zs += __shfl_xor(Zs, o);
                Tn += __shfl_xor(Tn, o);
            }
            if (lane == 0) {
                float kl = Tn / Zt - mt - __logf(Zt) + ms + __logf(Zs);
                float ax = fabsf(kl);
                float h = ax < 0.5f ? ax * ax : ax - 0.25f;
                atomicAdd(&res3[branch], h);
            }
        }
    }
    __syncthreads();
    if (t < 3) atomicAdd(&acc[t], res3[t]);
}

// ---------------- K4: finalize ----------------
__global__ void finalize_kernel(const float* __restrict__ acc, float* __restrict__ out) {
    out[0] = acc[0] / 3072.f + acc[1] / 12288.f + acc[2] / 12288.f;
}

extern "C" void kernel_launch(void* const* d_in, const int* in_sizes, int n_in,
                              void* d_out, int out_size, void* d_ws, size_t ws_size,
                              hipStream_t stream) {
    const float* teacher = (const float*)d_in[0];
    const float* student = (const float*)d_in[1];
    const int* ref_perm = (const int*)d_in[2];
    const int* shared_perm = (const int*)d_in[3];
    float* out = (float*)d_out;

    char* ws = (char*)d_ws;
    float* acc     = (float*)ws;                         // 64 B
    float* invnorm = (float*)(ws + 64);                  // 16384 floats
    __bf16* Abf    = (__bf16*)(ws + 64 + 65536 + 16384); // 4*256*1024
    __bf16* Bbf    = Abf + (size_t)4 * 256 * 1024;       // 4*4096*1024
    __bf16* scoresb = Bbf + (size_t)4 * 4096 * 1024;     // 4*256*4096

    convert_kernel<<<BATCH * 4352, 256, 0, stream>>>(teacher, ref_perm, Abf, Bbf, invnorm, acc);
    mfma_gemm_kernel<<<dim3(32, 2, 4), 512, 0, stream>>>(Abf, Bbf, scoresb);
    topk_kl_kernel<<<1024, 256, 0, stream>>>(scoresb, teacher, student, ref_perm, shared_perm, invnorm, acc);
    finalize_kernel<<<1, 1, 0, stream>>>(acc, out);
}